// Round 5
// baseline (150.206 us; speedup 1.0000x reference)
//
#include <hip/hip_runtime.h>
#include <math.h>

// QLSTM fused single-kernel version.
//
// qgate(x,p)[b,w] = prod_{j<=w} cos(p[j,1]) * cos(p[j,0] + x[b,j])
// (RX(p0)RX(x)=RX(p0+x); product state; CNOT chain -> Z_0..Z_w in Heisenberg
// picture; expectations factorize.)
//
// Round 10 (this session): TWO BATCHES PER WAVE. The recurrence step is
// exposed-latency-bound: ~790 cyc/step with only ~105 cyc of VALU issue --
// the wave idles ~85% of each step on its own dependency chain. Different
// batches' chains are independent, so one wave now interleaves TWO batch
// recurrences: chain B's instructions fill chain A's stalls. Per-batch
// instruction stream and fma order are identical to R9 -> absmax bitwise
// unchanged. Shared lane constants (whp, p0, cp1, S, A, ln) are batch-
// independent; only hn/cc/hterm/z-regs duplicate. LDS = Wl 10K + 2x Zl
// 21.1K + 2x ys_l 5.4K + bl = 63.4 KB (fits 64 KB static -> N=2 max).
// Grid: 128 blocks x 256 threads (phase 1: 256 rows, 1 row/thread as
// before); wave 0 runs both chains.

#define T_STEPS 128
#define B_SZ    256
#define D_IN    64
#define H_SZ    10
#define COMB    74   // D_IN + H_SZ
#define ZPAD    132  // Z row stride (floats); breaks the 64-way bank collision
#define ZTILE   (40 * ZPAD)
#define YSTILE  (T_STEPS * H_SZ + 64)   // +64 pad: all-lane stores spill here

__device__ __forceinline__ float rdlane(float v, int lane) {
    return __int_as_float(__builtin_amdgcn_readlane(__float_as_int(v), lane));
}
__device__ __forceinline__ float frcp(float x) { return __builtin_amdgcn_rcpf(x); }

// Pade [5/4] tanh: exact-to-1e-4 on |x| <= ~2.5 (all our inputs are bounded:
// |prod|<=1 -> f,i<=0.7311, |u|<=0.7616 -> |cc| <= 0.557/(1-0.7311) = 2.07)
__device__ __forceinline__ float tanh_pade(float x) {
    float x2  = x * x;
    float num = x * fmaf(x2, (x2 + 105.f), 945.f);
    float den = fmaf(x2, fmaf(x2, 15.f, 420.f), 945.f);
    return num * frcp(den);
}

// One recurrence step (identical math + instruction pattern to R9).
__device__ __forceinline__ void qstep(
    float zsv, int t, float& hn, float& cc, float& hterm, float* ysl,
    float cp1, float p0, float s0, float s1, float sc,
    const float (&whp)[H_SZ], float Sln, float Aln, float lng, float lnb,
    bool act)
{
    float z = zsv + hterm;

    // per-wire <Z> factor, segmented inclusive cumprod (fused DPP muls;
    // bound_ctrl off: invalid lanes keep dest == mul-by-1.0 identity)
    float prod = cp1 * __cosf(p0 + z);
    asm("s_nop 1\n\t"
        "v_mul_f32_dpp %0, %0, %0 row_shr:1 row_mask:0xf bank_mask:0xf\n\t"
        "s_nop 1\n\t"
        "v_mul_f32_dpp %0, %0, %0 row_shr:2 row_mask:0xf bank_mask:0xf\n\t"
        "s_nop 1\n\t"
        "v_mul_f32_dpp %0, %0, %0 row_shr:4 row_mask:0xf bank_mask:0xf\n\t"
        "s_nop 1\n\t"
        "v_mul_f32_dpp %0, %0, %0 row_shr:8 row_mask:0xf bank_mask:0xf"
        : "+v"(prod));

    // branchless activation via Pade tanh (|prod| <= 1)
    float av = fmaf(s1, tanh_pade(sc * prod), s0);

    // gather the 4 gates' activations for this lane's w (VALU permlanes)
    float a_ = av, b_ = av;
    asm("s_nop 1\n\t"
        "v_permlane32_swap_b32 %0, %1" : "+v"(a_), "+v"(b_));
    float F_ = a_, I_ = a_;
    asm("s_nop 1\n\t"
        "v_permlane16_swap_b32 %0, %1" : "+v"(F_), "+v"(I_));
    float U_ = b_, O_ = b_;
    asm("s_nop 1\n\t"
        "v_permlane16_swap_b32 %0, %1" : "+v"(U_), "+v"(O_));

    cc = fmaf(F_, cc, I_ * U_);
    float tc   = tanh_pade(cc);             // |cc| <= 2.07 (bounded)
    float hraw = fmaf(O_, tc, hn);          // residual skip

    // LN stats: fused in-place DPP row_ror reduce, v1/v2 interleaved
    float v1 = act ? hraw : 0.f;
    float v2 = v1 * v1;
    asm("s_nop 1\n\t"
        "v_add_f32_dpp %0, %0, %0 row_ror:8 row_mask:0xf bank_mask:0xf\n\t"
        "v_add_f32_dpp %1, %1, %1 row_ror:8 row_mask:0xf bank_mask:0xf\n\t"
        "s_nop 0\n\t"
        "v_add_f32_dpp %0, %0, %0 row_ror:4 row_mask:0xf bank_mask:0xf\n\t"
        "v_add_f32_dpp %1, %1, %1 row_ror:4 row_mask:0xf bank_mask:0xf\n\t"
        "s_nop 0\n\t"
        "v_add_f32_dpp %0, %0, %0 row_ror:2 row_mask:0xf bank_mask:0xf\n\t"
        "v_add_f32_dpp %1, %1, %1 row_ror:2 row_mask:0xf bank_mask:0xf\n\t"
        "s_nop 0\n\t"
        "v_add_f32_dpp %0, %0, %0 row_ror:1 row_mask:0xf bank_mask:0xf\n\t"
        "v_add_f32_dpp %1, %1, %1 row_ror:1 row_mask:0xf bank_mask:0xf"
        : "+v"(v1), "+v"(v2));

    // D = sum_j wh'[j]*hraw[j] via readlane (overlaps the DPP reduce)
    float d0 = whp[0] * rdlane(hraw, 0);
    float d1 = whp[1] * rdlane(hraw, 1);
    d0 = fmaf(whp[2], rdlane(hraw, 2), d0);
    d1 = fmaf(whp[3], rdlane(hraw, 3), d1);
    d0 = fmaf(whp[4], rdlane(hraw, 4), d0);
    d1 = fmaf(whp[5], rdlane(hraw, 5), d1);
    d0 = fmaf(whp[6], rdlane(hraw, 6), d0);
    d1 = fmaf(whp[7], rdlane(hraw, 7), d1);
    d0 = fmaf(whp[8], rdlane(hraw, 8), d0);
    d1 = fmaf(whp[9], rdlane(hraw, 9), d1);
    float D = d0 + d1;

    float mu   = v1 * 0.1f;
    float varr = fmaxf(fmaf(v2, 0.1f, -mu * mu), 0.f);
    float rstd = __builtin_amdgcn_rsqf(varr + 1e-5f);

    hn    = fmaf((hraw - mu) * rstd, lng, lnb);
    hterm = fmaf(rstd, fmaf(-mu, Sln, D), Aln);

    // stage to LDS, all 64 lanes (lanes >= 10 pre-write future slots that
    // valid writes overwrite in order; final-step spill lands in the pad)
    ysl[t * H_SZ] = hn;
}

__global__ __launch_bounds__(256) void qlstm_fused(
    const float* __restrict__ x,
    const float* __restrict__ Wf, const float* __restrict__ bf, const float* __restrict__ pf,
    const float* __restrict__ Wi, const float* __restrict__ bi, const float* __restrict__ pi,
    const float* __restrict__ Wu, const float* __restrict__ bu, const float* __restrict__ pu,
    const float* __restrict__ Wo, const float* __restrict__ bo, const float* __restrict__ po,
    const float* __restrict__ ln_g, const float* __restrict__ ln_b,
    float* __restrict__ ys, float* __restrict__ outH, float* __restrict__ outC)
{
    __shared__ __align__(16) float Wl[40 * 64];        // 10.0 KB
    __shared__ __align__(16) float Zl[2 * ZTILE];      // 42.2 KB
    __shared__ __align__(16) float ys_l[2 * YSTILE];   // 10.75 KB
    __shared__ float bl[40];
    // total 63.4 KB < 64 KB static limit

    const int tid = threadIdx.x;      // 0..255
    const int bs  = tid >> 7;         // sub-batch 0/1 (phase 1 row owner)
    const int tt  = tid & 127;        // t-row
    const int b0  = blockIdx.x * 2;   // batches b0, b0+1

    // ---- phase 0: x row (t=tt, batch=b0+bs) into regs ----------------------
    float xr[64];
    const float4* xin = (const float4*)(x + ((size_t)tt * B_SZ + (b0 + bs)) * D_IN);
#pragma unroll
    for (int k = 0; k < 16; k++) {
        float4 v = xin[k];
        xr[4*k+0] = v.x; xr[4*k+1] = v.y; xr[4*k+2] = v.z; xr[4*k+3] = v.w;
    }

    // ---- stage W,b into LDS (r wave-uniform -> scalar branches) ------------
#pragma unroll
    for (int k = 0; k < 10; k++) {
        int idx = k * 256 + tid;
        int r   = idx >> 6;        // row 0..39, uniform within each wave
        int col = idx & 63;
        const float* Wp; int w;
        if      (r < 10) { Wp = Wf; w = r;      }
        else if (r < 20) { Wp = Wi; w = r - 10; }
        else if (r < 30) { Wp = Wu; w = r - 20; }
        else             { Wp = Wo; w = r - 30; }
        Wl[idx] = Wp[w * COMB + col];
    }
    if (tid < 40) {
        int r = tid;
        const float* bp; int w;
        if      (r < 10) { bp = bf; w = r;      }
        else if (r < 20) { bp = bi; w = r - 10; }
        else if (r < 30) { bp = bu; w = r - 20; }
        else             { bp = bo; w = r - 30; }
        bl[tid] = bp[w];
    }
    __syncthreads();

    // ---- phase 1: Z[bs][gw][tt] = b[gw] + x[tt,b0+bs,:].W[gw,0:64] ---------
    // identical fma order to previous rounds -> bitwise-identical Z
    float* Zt = Zl + bs * ZTILE;
#pragma unroll
    for (int gw = 0; gw < 40; gw++) {
        float a = bl[gw];
        const float4* wr4 = (const float4*)(Wl + gw * 64);  // uniform b128
#pragma unroll
        for (int d4 = 0; d4 < 16; d4++) {
            float4 wv = wr4[d4];
            a = fmaf(xr[4*d4+0], wv.x, a);
            a = fmaf(xr[4*d4+1], wv.y, a);
            a = fmaf(xr[4*d4+2], wv.z, a);
            a = fmaf(xr[4*d4+3], wv.w, a);
        }
        Zt[gw * ZPAD + tt] = a;   // stride-1 across lanes: conflict-free
    }
    __syncthreads();

    if (tid >= 64) return;         // waves 1-3 done; wave 0 runs both chains

    // ---- phase 2: TWO interleaved sequential recurrences -------------------
    const int lane = tid;
    const int g    = lane >> 4;        // gate 0..3 = f,i,u,o
    const int w    = lane & 15;        // wire 0..15 (10 active)
    const bool act = (w < H_SZ);

    const float* Ws[4] = {Wf, Wi, Wu, Wo};
    const float* ps[4] = {pf, pi, pu, po};

    // LN folded into the recurrence (batch-independent lane constants):
    //   sum_j wh[j]*hnew[j] = rstd*(sum_j wh'[j]*hraw[j] - mu*S) + A
    float whp[H_SZ];
    float S = 0.f, A = 0.f;
#pragma unroll
    for (int j = 0; j < H_SZ; j++) {
        float whj = act ? Ws[g][w * COMB + D_IN + j] : 0.f;
        whp[j] = whj * ln_g[j];
        S += whp[j];
        A  = fmaf(whj, ln_b[j], A);
    }
    const float p0  = act ? ps[g][w * 3 + 0] : 0.f;
    const float cp1 = act ? __cosf(ps[g][w * 3 + 1]) : 1.f;
    const float lng = act ? ln_g[w] : 0.f;
    const float lnb = act ? ln_b[w] : 0.f;
    // gate u (g==2): tanh(q); others: sigmoid(q) = 0.5 + 0.5*tanh(q/2)
    const float s0 = (g == 2) ? 0.f : 0.5f;
    const float s1 = (g == 2) ? 1.f : 0.5f;
    const float sc = (g == 2) ? 1.f : 0.5f;

    // per-chain state (named scalars: no runtime-indexed arrays -> no scratch)
    float hn0 = 0.f, cc0 = 0.f, ht0 = 0.f;
    float hn1 = 0.f, cc1 = 0.f, ht1 = 0.f;

    const int gwl = g * 10 + (act ? w : 9);
    const float* zbA = Zl + gwl * ZPAD;            // chain 0 z-stream
    const float* zbB = Zl + ZTILE + gwl * ZPAD;    // chain 1 z-stream
    float4 a_zb0 = *(const float4*)(zbA);
    float4 a_zb1 = *(const float4*)(zbA + 4);
    float4 b_zb0 = *(const float4*)(zbB);
    float4 b_zb1 = *(const float4*)(zbB + 4);

    float* yslA = ys_l + lane;
    float* yslB = ys_l + YSTILE + lane;

    for (int gq = 0; gq < T_STEPS / 4; gq++) {
        float4 zcA = a_zb0; a_zb0 = a_zb1;
        float4 zcB = b_zb0; b_zb0 = b_zb1;
        const int nl = (gq + 2 < T_STEPS / 4) ? gq + 2 : T_STEPS / 4 - 1;
        a_zb1 = *(const float4*)(zbA + (size_t)nl * 4);
        b_zb1 = *(const float4*)(zbB + (size_t)nl * 4);

        float zsA[4] = {zcA.x, zcA.y, zcA.z, zcA.w};
        float zsB[4] = {zcB.x, zcB.y, zcB.z, zcB.w};
#pragma unroll
        for (int j = 0; j < 4; j++) {
            const int t = gq * 4 + j;
            // two independent chains: B's instructions fill A's stalls
            qstep(zsA[j], t, hn0, cc0, ht0, yslA,
                  cp1, p0, s0, s1, sc, whp, S, A, lng, lnb, act);
            qstep(zsB[j], t, hn1, cc1, ht1, yslB,
                  cp1, p0, s0, s1, sc, whp, S, A, lng, lnb, act);
        }
    }

    // ---- epilogue: bulk dump ys_l -> global (pipelined, off the chain) -----
#pragma unroll
    for (int k = 0; k < 20; k++) {
        int idx = k * 64 + lane;           // 0..1279
        int t   = idx / H_SZ;
        int ww  = idx - t * H_SZ;
        size_t go = (size_t)t * B_SZ * H_SZ + (size_t)b0 * H_SZ + ww;
        ys[go]            = ys_l[idx];
        ys[go + H_SZ]     = ys_l[YSTILE + idx];
    }

    if (lane < H_SZ) {
        outH[(b0 + 0) * H_SZ + lane] = hn0;
        outC[(b0 + 0) * H_SZ + lane] = cc0;
        outH[(b0 + 1) * H_SZ + lane] = hn1;
        outC[(b0 + 1) * H_SZ + lane] = cc1;
    }
}

extern "C" void kernel_launch(void* const* d_in, const int* in_sizes, int n_in,
                              void* d_out, int out_size, void* d_ws, size_t ws_size,
                              hipStream_t stream)
{
    const float* x    = (const float*)d_in[0];
    const float* Wf   = (const float*)d_in[1];
    const float* bf   = (const float*)d_in[2];
    const float* pf   = (const float*)d_in[3];
    const float* Wi   = (const float*)d_in[4];
    const float* bi   = (const float*)d_in[5];
    const float* pi   = (const float*)d_in[6];
    const float* Wu   = (const float*)d_in[7];
    const float* bu   = (const float*)d_in[8];
    const float* pu   = (const float*)d_in[9];
    const float* Wo   = (const float*)d_in[10];
    const float* bo   = (const float*)d_in[11];
    const float* po   = (const float*)d_in[12];
    const float* ln_g = (const float*)d_in[13];
    const float* ln_b = (const float*)d_in[14];

    float* ys   = (float*)d_out;              // (T,B,H)
    float* outH = ys + (size_t)T_STEPS * B_SZ * H_SZ;
    float* outC = outH + (size_t)B_SZ * H_SZ;

    qlstm_fused<<<B_SZ / 2, 256, 0, stream>>>(
        x, Wf, bf, pf, Wi, bi, pi, Wu, bu, pu, Wo, bo, po,
        ln_g, ln_b, ys, outH, outC);
}

// Round 7
// 124.205 us; speedup vs baseline: 1.2093x; 1.2093x over previous
//
#include <hip/hip_runtime.h>
#include <math.h>

// QLSTM fused single-kernel version.
//
// qgate(x,p)[b,w] = prod_{j<=w} cos(p[j,1]) * cos(p[j,0] + x[b,j])
// (RX(p0)RX(x)=RX(p0+x); product state; CNOT chain -> Z_0..Z_w in Heisenberg
// picture; expectations factorize.)
//
// Round 12 (this session): resubmission of R11 — the R11 bench died with an
// infra-side Trio ExceptionGroup (no kernel verdict, no profile); no evidence
// against the kernel. R11 content: R9 structure (best: 45.2 us kernel) plus
// critical-path trims in the LN tail (v1 -> mu -> varr -> rsq -> hterm feeds
// the next step's z):
//   - rstd = rsq(fmaf(v2,0.1,fmaf(-mu,mu,1e-5))): folds away fmax and the
//     +1e-5 add (-8 cyc, -2 instr). Positivity safe: var >= -1e-8 rounding,
//     +1e-5 dominates.
//   - hraw-mu precomputed before rstd arrives (hn is off the critical path;
//     only hterm feeds the next step).

#define T_STEPS 128
#define B_SZ    256
#define D_IN    64
#define H_SZ    10
#define COMB    74   // D_IN + H_SZ
#define ZPAD    132  // Z row stride (floats); 132*4=528 B keeps b128 16B-aligned

__device__ __forceinline__ float rdlane(float v, int lane) {
    return __int_as_float(__builtin_amdgcn_readlane(__float_as_int(v), lane));
}
__device__ __forceinline__ float frcp(float x) { return __builtin_amdgcn_rcpf(x); }

// Pade [5/4] tanh: exact-to-1e-4 on |x| <= ~2.5 (all our inputs are bounded:
// |prod|<=1 -> f,i<=0.7311, |u|<=0.7616 -> |cc| <= 0.557/(1-0.7311) = 2.07)
__device__ __forceinline__ float tanh_pade(float x) {
    float x2  = x * x;
    float num = x * fmaf(x2, (x2 + 105.f), 945.f);
    float den = fmaf(x2, fmaf(x2, 15.f, 420.f), 945.f);
    return num * frcp(den);
}

__global__ __launch_bounds__(128) void qlstm_fused(
    const float* __restrict__ x,
    const float* __restrict__ Wf, const float* __restrict__ bf, const float* __restrict__ pf,
    const float* __restrict__ Wi, const float* __restrict__ bi, const float* __restrict__ pi,
    const float* __restrict__ Wu, const float* __restrict__ bu, const float* __restrict__ pu,
    const float* __restrict__ Wo, const float* __restrict__ bo, const float* __restrict__ po,
    const float* __restrict__ ln_g, const float* __restrict__ ln_b,
    float* __restrict__ ys, float* __restrict__ outH, float* __restrict__ outC)
{
    __shared__ __align__(16) float Wl[40 * 64];
    __shared__ __align__(16) float Zl[40 * ZPAD];            // 21.1 KB
    __shared__ __align__(16) float ys_l[T_STEPS * H_SZ + 64]; // +64 pad: lanes>=10 spill
    __shared__ float bl[40];

    const int tid = threadIdx.x;   // 0..127; t-row owner in phase 1
    const int b   = blockIdx.x;    // batch

    // ---- phase 0: x row t=tid into regs (issue global loads early) ---------
    float xr[64];
    const float4* xin = (const float4*)(x + ((size_t)tid * B_SZ + b) * D_IN);
#pragma unroll
    for (int k = 0; k < 16; k++) {
        float4 v = xin[k];
        xr[4*k+0] = v.x; xr[4*k+1] = v.y; xr[4*k+2] = v.z; xr[4*k+3] = v.w;
    }

    // ---- stage W,b into LDS (r = 2k + tid/64 is wave-uniform -> scalar br) -
#pragma unroll
    for (int k = 0; k < 20; k++) {
        int idx = k * 128 + tid;
        int r   = idx >> 6;        // row 0..39, uniform within each wave
        int col = idx & 63;
        const float* Wp; int w;
        if      (r < 10) { Wp = Wf; w = r;      }
        else if (r < 20) { Wp = Wi; w = r - 10; }
        else if (r < 30) { Wp = Wu; w = r - 20; }
        else             { Wp = Wo; w = r - 30; }
        Wl[idx] = Wp[w * COMB + col];
    }
    if (tid < 40) {
        int r = tid;
        const float* bp; int w;
        if      (r < 10) { bp = bf; w = r;      }
        else if (r < 20) { bp = bi; w = r - 10; }
        else if (r < 30) { bp = bu; w = r - 20; }
        else             { bp = bo; w = r - 30; }
        bl[tid] = bp[w];
    }
    __syncthreads();

    // ---- phase 1: Z[gw][t] = b[gw] + x[t,b,:].W[gw,0:64]  (t = tid) --------
    // identical fma order to previous rounds -> bitwise-identical Z
#pragma unroll
    for (int gw = 0; gw < 40; gw++) {
        float a = bl[gw];
        const float4* wr4 = (const float4*)(Wl + gw * 64);  // uniform b128
#pragma unroll
        for (int d4 = 0; d4 < 16; d4++) {
            float4 wv = wr4[d4];
            a = fmaf(xr[4*d4+0], wv.x, a);
            a = fmaf(xr[4*d4+1], wv.y, a);
            a = fmaf(xr[4*d4+2], wv.z, a);
            a = fmaf(xr[4*d4+3], wv.w, a);
        }
        Zl[gw * ZPAD + tid] = a;   // banks (4*gw + t)%32: conflict-free
    }
    __syncthreads();

    if (tid >= 64) return;         // wave 1 done; wave 0 runs the recurrence

    // ---- phase 2: sequential recurrence ------------------------------------
    const int lane = tid;
    const int g    = lane >> 4;        // gate 0..3 = f,i,u,o
    const int w    = lane & 15;        // wire 0..15 (10 active)
    const bool act = (w < H_SZ);

    const float* Ws[4] = {Wf, Wi, Wu, Wo};
    const float* ps[4] = {pf, pi, pu, po};

    // LN folded into the recurrence:
    //   sum_j wh[j]*hnew[j] = rstd*(sum_j wh'[j]*hraw[j] - mu*S) + A
    float whp[H_SZ];
    float S = 0.f, A = 0.f;
#pragma unroll
    for (int j = 0; j < H_SZ; j++) {
        float whj = act ? Ws[g][w * COMB + D_IN + j] : 0.f;
        whp[j] = whj * ln_g[j];
        S += whp[j];
        A  = fmaf(whj, ln_b[j], A);
    }
    const float p0  = act ? ps[g][w * 3 + 0] : 0.f;
    const float cp1 = act ? __cosf(ps[g][w * 3 + 1]) : 1.f;
    const float lng = act ? ln_g[w] : 0.f;
    const float lnb = act ? ln_b[w] : 0.f;
    // gate u (g==2): tanh(q); others: sigmoid(q) = 0.5 + 0.5*tanh(q/2)
    const float s0 = (g == 2) ? 0.f : 0.5f;
    const float s1 = (g == 2) ? 1.f : 0.5f;
    const float sc = (g == 2) ? 1.f : 0.5f;

    float hn = 0.f;      // normalized h[w] (valid in lanes 0..9)
    float cc = 0.f;      // c[w]
    float hterm = 0.f;   // sum_j wh[j]*h[j] contribution to this lane's z

    // z stream comes from LDS: per-lane row gwl, contiguous in t.
    const int gwl = g * 10 + (act ? w : 9);
    const float* zb = Zl + (size_t)gwl * ZPAD;
    float4 zb0 = *(const float4*)(zb);
    float4 zb1 = *(const float4*)(zb + 4);

    // per-lane LDS base for the ys staging tile
    float* ysl = ys_l + lane;

    for (int gq = 0; gq < T_STEPS / 4; gq++) {
        float4 zc = zb0;
        zb0 = zb1;
        const int nl = (gq + 2 < T_STEPS / 4) ? gq + 2 : T_STEPS / 4 - 1;
        zb1 = *(const float4*)(zb + (size_t)nl * 4);

        float zs[4] = {zc.x, zc.y, zc.z, zc.w};
#pragma unroll
        for (int j = 0; j < 4; j++) {
            const int t = gq * 4 + j;
            float z = zs[j] + hterm;

            // per-wire <Z> factor, segmented inclusive cumprod.
            // Fused in-place DPP muls: invalid lanes (row-lane < shift) keep
            // dest (bound_ctrl off) == old mul-by-1.0 identity, bitwise equal.
            float prod = cp1 * __cosf(p0 + z);
            asm("s_nop 1\n\t"
                "v_mul_f32_dpp %0, %0, %0 row_shr:1 row_mask:0xf bank_mask:0xf\n\t"
                "s_nop 1\n\t"
                "v_mul_f32_dpp %0, %0, %0 row_shr:2 row_mask:0xf bank_mask:0xf\n\t"
                "s_nop 1\n\t"
                "v_mul_f32_dpp %0, %0, %0 row_shr:4 row_mask:0xf bank_mask:0xf\n\t"
                "s_nop 1\n\t"
                "v_mul_f32_dpp %0, %0, %0 row_shr:8 row_mask:0xf bank_mask:0xf"
                : "+v"(prod));

            // branchless activation via Pade tanh (|prod| <= 1)
            float av = fmaf(s1, tanh_pade(sc * prod), s0);

            // gather the 4 gates' activations for this lane's w — VALU-pipe
            // permlane swaps (bit-identical to a ds_bpermute gather):
            //   a = av[lane&31] ({f,i} by row parity), bb = av[lane|32] ({u,o})
            float a_ = av, b_ = av;
            asm("s_nop 1\n\t"
                "v_permlane32_swap_b32 %0, %1" : "+v"(a_), "+v"(b_));
            float F_ = a_, I_ = a_;   // F: f_w in all lanes, I: i_w in all lanes
            asm("s_nop 1\n\t"
                "v_permlane16_swap_b32 %0, %1" : "+v"(F_), "+v"(I_));
            float U_ = b_, O_ = b_;   // U: u_w, O: o_w
            asm("s_nop 1\n\t"
                "v_permlane16_swap_b32 %0, %1" : "+v"(U_), "+v"(O_));

            cc = fmaf(F_, cc, I_ * U_);
            float tc   = tanh_pade(cc);             // |cc| <= 2.07 (bounded)
            float hraw = fmaf(O_, tc, hn);          // residual skip

            // LN stats: fused in-place DPP row_ror reduce, v1/v2 interleaved
            float v1 = act ? hraw : 0.f;
            float v2 = v1 * v1;
            asm("s_nop 1\n\t"
                "v_add_f32_dpp %0, %0, %0 row_ror:8 row_mask:0xf bank_mask:0xf\n\t"
                "v_add_f32_dpp %1, %1, %1 row_ror:8 row_mask:0xf bank_mask:0xf\n\t"
                "s_nop 0\n\t"
                "v_add_f32_dpp %0, %0, %0 row_ror:4 row_mask:0xf bank_mask:0xf\n\t"
                "v_add_f32_dpp %1, %1, %1 row_ror:4 row_mask:0xf bank_mask:0xf\n\t"
                "s_nop 0\n\t"
                "v_add_f32_dpp %0, %0, %0 row_ror:2 row_mask:0xf bank_mask:0xf\n\t"
                "v_add_f32_dpp %1, %1, %1 row_ror:2 row_mask:0xf bank_mask:0xf\n\t"
                "s_nop 0\n\t"
                "v_add_f32_dpp %0, %0, %0 row_ror:1 row_mask:0xf bank_mask:0xf\n\t"
                "v_add_f32_dpp %1, %1, %1 row_ror:1 row_mask:0xf bank_mask:0xf"
                : "+v"(v1), "+v"(v2));

            // D = sum_j wh'[j]*hraw[j] via readlane (overlaps the DPP reduce)
            float d0 = whp[0] * rdlane(hraw, 0);
            float d1 = whp[1] * rdlane(hraw, 1);
            d0 = fmaf(whp[2], rdlane(hraw, 2), d0);
            d1 = fmaf(whp[3], rdlane(hraw, 3), d1);
            d0 = fmaf(whp[4], rdlane(hraw, 4), d0);
            d1 = fmaf(whp[5], rdlane(hraw, 5), d1);
            d0 = fmaf(whp[6], rdlane(hraw, 6), d0);
            d1 = fmaf(whp[7], rdlane(hraw, 7), d1);
            d0 = fmaf(whp[8], rdlane(hraw, 8), d0);
            d1 = fmaf(whp[9], rdlane(hraw, 9), d1);
            float D = d0 + d1;

            // LN tail (critical path: v1 -> mu -> rstd -> hterm -> next z).
            // fmax+add folded into the rsq argument: var >= -1e-8 rounding,
            // +1e-5 dominates -> always positive.
            float mu   = v1 * 0.1f;
            float rstd = __builtin_amdgcn_rsqf(
                             fmaf(v2, 0.1f, fmaf(-mu, mu, 1e-5f)));
            float hc   = hraw - mu;               // ready before rstd lands

            hn    = fmaf(hc * rstd, lng, lnb);    // off the critical path
            hterm = fmaf(rstd, fmaf(-mu, S, D), A);

            // stage to LDS, all 64 lanes (lanes >= 10 pre-write future slots
            // that valid writes overwrite in order; spill lands in the pad)
            ysl[t * H_SZ] = hn;
        }
    }

    // ---- epilogue: bulk dump ys_l -> global (pipelined, off the chain) -----
#pragma unroll
    for (int k = 0; k < 20; k++) {
        int idx = k * 64 + lane;           // 0..1279
        int t   = idx / H_SZ;
        int ww  = idx - t * H_SZ;
        ys[(size_t)t * B_SZ * H_SZ + (size_t)b * H_SZ + ww] = ys_l[idx];
    }

    if (lane < H_SZ) {
        outH[b * H_SZ + lane] = hn;
        outC[b * H_SZ + lane] = cc;
    }
}

extern "C" void kernel_launch(void* const* d_in, const int* in_sizes, int n_in,
                              void* d_out, int out_size, void* d_ws, size_t ws_size,
                              hipStream_t stream)
{
    const float* x    = (const float*)d_in[0];
    const float* Wf   = (const float*)d_in[1];
    const float* bf   = (const float*)d_in[2];
    const float* pf   = (const float*)d_in[3];
    const float* Wi   = (const float*)d_in[4];
    const float* bi   = (const float*)d_in[5];
    const float* pi   = (const float*)d_in[6];
    const float* Wu   = (const float*)d_in[7];
    const float* bu   = (const float*)d_in[8];
    const float* pu   = (const float*)d_in[9];
    const float* Wo   = (const float*)d_in[10];
    const float* bo   = (const float*)d_in[11];
    const float* po   = (const float*)d_in[12];
    const float* ln_g = (const float*)d_in[13];
    const float* ln_b = (const float*)d_in[14];

    float* ys   = (float*)d_out;              // (T,B,H)
    float* outH = ys + (size_t)T_STEPS * B_SZ * H_SZ;
    float* outC = outH + (size_t)B_SZ * H_SZ;

    qlstm_fused<<<B_SZ, 128, 0, stream>>>(
        x, Wf, bf, pf, Wi, bi, pi, Wu, bu, pu, Wo, bo, po,
        ln_g, ln_b, ys, outH, outC);
}